// Round 9
// baseline (230.855 us; speedup 1.0000x reference)
//
#include <hip/hip_runtime.h>

#define DD 128

using bf16 = __bf16;
typedef __bf16 bf16x8 __attribute__((ext_vector_type(8)));
typedef float f32x4 __attribute__((ext_vector_type(4)));

__device__ inline bf16x8 cvt8(const float* p) {
  f32x4 v0 = *(const f32x4*)p;
  f32x4 v1 = *(const f32x4*)(p + 4);
  bf16x8 r;
  r[0] = (bf16)v0[0]; r[1] = (bf16)v0[1]; r[2] = (bf16)v0[2]; r[3] = (bf16)v0[3];
  r[4] = (bf16)v1[0]; r[5] = (bf16)v1[1]; r[6] = (bf16)v1[2]; r[7] = (bf16)v1[3];
  return r;
}

// fast tanh: 1 - 2/(e^{2x}+1); v_exp + v_rcp, saturates correctly at +-1
__device__ inline float ftanh(float x) {
  float e2 = __expf(2.0f * x);
  return 1.0f - 2.0f * __builtin_amdgcn_rcpf(e2 + 1.0f);
}

// XOR swizzle for [128 rows][256 B] LDS tiles (G4): spreads 16-row b128
// reads across banks; involution, keeps 16-B alignment.
__device__ inline int swz(int o) { return o ^ (((o >> 8) & 7) << 4); }

// ---- fused prologue: zero cnt | weights->bf16 | x->bf16 ------------------
__global__ void k_prep(int* __restrict__ cnt, int N,
                       const float* __restrict__ w0, const float* __restrict__ w1,
                       const float* __restrict__ w2, const float* __restrict__ w3,
                       const float* __restrict__ w4, bf16* __restrict__ wb, int totalW,
                       const float* __restrict__ x, bf16* __restrict__ xb, int total8,
                       int nbZ, int nbW) {
  int b = blockIdx.x;
  if (b < nbZ) {
    int i = b * 256 + threadIdx.x;
    if (i < N) cnt[i] = 0;
  } else if (b < nbZ + nbW) {
    int i = (b - nbZ) * 256 + threadIdx.x;
    if (i < totalW) {
      int m = i >> 14;           // DD*DD = 16384
      int r = i & 16383;
      const float* s = m == 0 ? w0 : m == 1 ? w1 : m == 2 ? w2 : m == 3 ? w3 : w4;
      wb[i] = (bf16)s[r];
    }
  } else {
    int i = (b - nbZ - nbW) * 256 + threadIdx.x;
    if (i < total8) *(bf16x8*)(xb + (size_t)i * 8) = cvt8(x + (size_t)i * 8);
  }
}

// ---- CSR build ----------------------------------------------------------
__global__ void k_hist(const int* __restrict__ dst, int* __restrict__ cnt, int E) {
  int e = blockIdx.x * 256 + threadIdx.x;
  if (e < E) atomicAdd(&cnt[dst[e]], 1);
}

__global__ __launch_bounds__(256) void k_scan1(const int* __restrict__ cnt,
                                               int* __restrict__ bsum, int N) {
  __shared__ int sm[256];
  int t = threadIdx.x;
  int i = blockIdx.x * 256 + t;
  sm[t] = (i < N) ? cnt[i] : 0;
  __syncthreads();
#pragma unroll
  for (int d = 128; d > 0; d >>= 1) {
    if (t < d) sm[t] += sm[t + d];
    __syncthreads();
  }
  if (t == 0) bsum[blockIdx.x] = sm[0];
}

__global__ __launch_bounds__(256) void k_scan2(int* __restrict__ bsum, int nb) {
  __shared__ int sm[256];
  int t = threadIdx.x;
  int v = (t < nb) ? bsum[t] : 0;
  sm[t] = v;
  __syncthreads();
#pragma unroll
  for (int d = 1; d < 256; d <<= 1) {
    int u = (t >= d) ? sm[t - d] : 0;
    __syncthreads();
    sm[t] += u;
    __syncthreads();
  }
  if (t < nb) bsum[t] = sm[t] - v;   // exclusive prefix
}

__global__ __launch_bounds__(256) void k_scan3(const int* __restrict__ cnt,
                                               const int* __restrict__ bsum,
                                               int* __restrict__ offs,
                                               int* __restrict__ cursor, int N) {
  __shared__ int sm[256];
  int t = threadIdx.x;
  int i = blockIdx.x * 256 + t;
  int v = (i < N) ? cnt[i] : 0;
  sm[t] = v;
  __syncthreads();
#pragma unroll
  for (int d = 1; d < 256; d <<= 1) {
    int u = (t >= d) ? sm[t - d] : 0;
    __syncthreads();
    sm[t] += u;
    __syncthreads();
  }
  int incl = sm[t];
  int base = bsum[blockIdx.x];
  if (i < N) {
    int ex = base + incl - v;
    offs[i] = ex;
    cursor[i] = ex;
    if (i == N - 1) offs[N] = base + incl;
  }
}

__global__ void k_scatter(const int* __restrict__ src, const int* __restrict__ dst,
                          int* __restrict__ cursor, int* __restrict__ ssrc, int E) {
  int e = blockIdx.x * 256 + threadIdx.x;
  if (e < E) {
    int d = dst[e];
    int p = atomicAdd(&cursor[d], 1);
    ssrc[p] = src[e];
  }
}

// ---- fused SAGE layer: aggregate + GEMM ---------------------------------
// Block = 512 threads (8 waves), Ws+Wn staged in 64 KB swizzled LDS.
// Each wave owns 16 nodes; each lane aggregates its node's neighbor mean
// directly into MFMA A-fragment registers. Neighbor loop unrolled x4 for
// memory-level parallelism (16 row-chunk loads in flight per lane).
// MODE 0: H1out[idx] = (bf16)v
// MODE 1: Out[idx] = Xres[idx] + (f32)Hb[idx] + 0.5*v   (res, f32)
template <int MODE>
__global__ __launch_bounds__(512, 1) void k_layer(const bf16* __restrict__ Hb,
                                                  const int* __restrict__ offs,
                                                  const int* __restrict__ ssrc,
                                                  const bf16* __restrict__ Wsb,
                                                  const bf16* __restrict__ Wnb,
                                                  const float* __restrict__ bias,
                                                  const float* __restrict__ Xres,
                                                  bf16* __restrict__ H1out,
                                                  float* __restrict__ Out, int N) {
  __shared__ char smem[65536];   // [2][128 rows][256 B], swizzled
  int t = threadIdx.x;
#pragma unroll
  for (int m = 0; m < 2; ++m) {
    const bf16* wsrc = m ? Wnb : Wsb;
#pragma unroll
    for (int it = 0; it < 4; ++it) {
      int o = (it * 512 + t) * 16;          // linear byte offset in matrix
      *(bf16x8*)(smem + m * 32768 + swz(o)) = *(const bf16x8*)(wsrc + o / 2);
    }
  }
  __syncthreads();

  int wv = t >> 6;
  int lane = t & 63;
  int tile = blockIdx.x * 8 + wv;
  int n0 = tile << 4;
  if (n0 >= N) return;
  int lr = lane & 15;
  int g = lane >> 4;
  int lk = g << 3;                          // k offset in elems (8-elem chunk)

  // A1 (self) fragments
  const bf16* a1p = Hb + (size_t)(n0 + lr) * DD + lk;
  bf16x8 a1[4];
#pragma unroll
  for (int kk = 0; kk < 4; ++kk) a1[kk] = *(const bf16x8*)(a1p + kk * 32);

  // aggregate neighbor mean for node n0+lr into A2 fragments (f32 acc)
  int node = n0 + lr;
  int beg = offs[node], end = offs[node + 1];
  float acc[4][8];
#pragma unroll
  for (int kk = 0; kk < 4; ++kk)
#pragma unroll
    for (int j = 0; j < 8; ++j) acc[kk][j] = 0.f;

  int i = beg;
  for (; i + 3 < end; i += 4) {             // 4 edges in flight per lane
    int s0 = ssrc[i], s1 = ssrc[i + 1], s2 = ssrc[i + 2], s3 = ssrc[i + 3];
    const bf16* p0 = Hb + (size_t)s0 * DD + lk;
    const bf16* p1 = Hb + (size_t)s1 * DD + lk;
    const bf16* p2 = Hb + (size_t)s2 * DD + lk;
    const bf16* p3 = Hb + (size_t)s3 * DD + lk;
    bf16x8 v0[4], v1[4], v2[4], v3[4];
#pragma unroll
    for (int kk = 0; kk < 4; ++kk) {
      v0[kk] = *(const bf16x8*)(p0 + kk * 32);
      v1[kk] = *(const bf16x8*)(p1 + kk * 32);
      v2[kk] = *(const bf16x8*)(p2 + kk * 32);
      v3[kk] = *(const bf16x8*)(p3 + kk * 32);
    }
#pragma unroll
    for (int kk = 0; kk < 4; ++kk)
#pragma unroll
      for (int j = 0; j < 8; ++j)
        acc[kk][j] += ((float)v0[kk][j] + (float)v1[kk][j]) +
                      ((float)v2[kk][j] + (float)v3[kk][j]);
  }
  for (; i < end; ++i) {                    // tail 0-3 edges
    int s = ssrc[i];
    const bf16* hp = Hb + (size_t)s * DD + lk;
#pragma unroll
    for (int kk = 0; kk < 4; ++kk) {
      bf16x8 v = *(const bf16x8*)(hp + kk * 32);
#pragma unroll
      for (int j = 0; j < 8; ++j) acc[kk][j] += (float)v[j];
    }
  }
  float inv = (end > beg) ? 1.0f / (float)(end - beg) : 0.f;
  bf16x8 a2[4];
#pragma unroll
  for (int kk = 0; kk < 4; ++kk)
#pragma unroll
    for (int j = 0; j < 8; ++j) a2[kk][j] = (bf16)(acc[kk][j] * inv);

  int rb = n0 + (g << 2);
#pragma unroll
  for (int j = 0; j < 8; ++j) {
    int row = j * 16 + lr;
    int rbase = row * 256 + lk * 2;         // byte offset of this lane's chunk
    f32x4 cs = {0.f, 0.f, 0.f, 0.f};
    f32x4 cn = {0.f, 0.f, 0.f, 0.f};
#pragma unroll
    for (int kk = 0; kk < 4; ++kk) {
      int ro = swz(rbase + kk * 64);
      bf16x8 bs = *(const bf16x8*)(smem + ro);
      bf16x8 bn = *(const bf16x8*)(smem + 32768 + ro);
      cs = __builtin_amdgcn_mfma_f32_16x16x32_bf16(a1[kk], bs, cs, 0, 0, 0);
      cn = __builtin_amdgcn_mfma_f32_16x16x32_bf16(a2[kk], bn, cn, 0, 0, 0);
    }
    int col = j * 16 + lr;
    float bb = bias[col];
#pragma unroll
    for (int r = 0; r < 4; ++r) {
      size_t idx = (size_t)(rb + r) * DD + col;
      float v = cs[r] + cn[r] + bb;
      if (MODE == 0) H1out[idx] = (bf16)v;
      else           Out[idx] = Xres[idx] + (float)Hb[idx] + 0.5f * v;
    }
  }
}

// ---- fused attention scores over both views -----------------------------
// wave parity selects view (0: res, 1: v2). Per-block partial sums -> ws.
__global__ __launch_bounds__(256) void k_attn2(const float* __restrict__ res,
                                               const float* __restrict__ v2f,
                                               const bf16* __restrict__ Wab,
                                               const float* __restrict__ bias,
                                               const float* __restrict__ att,
                                               float* __restrict__ partial,
                                               int nbA, int N) {
  int gwid = (int)((blockIdx.x * 256 + threadIdx.x) >> 6);
  int lane = threadIdx.x & 63;
  int view = gwid & 1;
  int tile = gwid >> 1;
  int n0 = tile << 4;
  float part = 0.f;
  if (n0 < N) {
    const float* Ef = view ? v2f : res;
    int lr = lane & 15;
    int lk = (lane >> 4) << 3;
    const float* ap = Ef + (size_t)(n0 + lr) * DD + lk;
    bf16x8 a[4];
#pragma unroll
    for (int kk = 0; kk < 4; ++kk) a[kk] = cvt8(ap + kk * 32);
#pragma unroll
    for (int j = 0; j < 8; ++j) {
      const bf16* wp = Wab + (size_t)(j * 16 + lr) * DD + lk;
      f32x4 c = {0.f, 0.f, 0.f, 0.f};
#pragma unroll
      for (int kk = 0; kk < 4; ++kk)
        c = __builtin_amdgcn_mfma_f32_16x16x32_bf16(a[kk], *(const bf16x8*)(wp + kk * 32), c, 0, 0, 0);
      int col = j * 16 + lr;
      float aw = att[col], bb = bias[col];
#pragma unroll
      for (int r = 0; r < 4; ++r) part += aw * ftanh(c[r] + bb);
    }
  }
#pragma unroll
  for (int d = 1; d < 64; d <<= 1) part += __shfl_xor(part, d);
  __shared__ float sm[4];
  int w = threadIdx.x >> 6;
  if (lane == 0) sm[w] = part;
  __syncthreads();
  if (threadIdx.x == 0) {
    partial[blockIdx.x]       = sm[0] + sm[2];   // view 0
    partial[nbA + blockIdx.x] = sm[1] + sm[3];   // view 1
  }
}

// ---- reduce partials -> scores[2] ---------------------------------------
__global__ __launch_bounds__(256) void k_score(const float* __restrict__ partial,
                                               float* __restrict__ scores, int nbA) {
  __shared__ float sm[256];
  int t = threadIdx.x;
#pragma unroll
  for (int v = 0; v < 2; ++v) {
    float s = 0.f;
    for (int i = t; i < nbA; i += 256) s += partial[v * nbA + i];
    sm[t] = s;
    __syncthreads();
#pragma unroll
    for (int d = 128; d > 0; d >>= 1) {
      if (t < d) sm[t] += sm[t + d];
      __syncthreads();
    }
    if (t == 0) scores[v] = sm[0];
    __syncthreads();
  }
}

// ---- final blend: out = b0*res + b1*view2 (in place on d_out) -----------
__global__ void k_fin(float* out, const float* __restrict__ v2,
                      const float* __restrict__ scores, float invN, int total4) {
  int i = blockIdx.x * 256 + threadIdx.x;
  if (i >= total4) return;
  float s0 = scores[0] * invN, s1 = scores[1] * invN;
  float m = fmaxf(s0, s1);
  float e0 = expf(s0 - m), e1 = expf(s1 - m);
  float inv = 1.0f / (e0 + e1);
  float b0 = e0 * inv, b1 = e1 * inv;
  f32x4 r = ((const f32x4*)out)[i];
  f32x4 w = ((const f32x4*)v2)[i];
  f32x4 o;
  o[0] = b0 * r[0] + b1 * w[0];
  o[1] = b0 * r[1] + b1 * w[1];
  o[2] = b0 * r[2] + b1 * w[2];
  o[3] = b0 * r[3] + b1 * w[3];
  ((f32x4*)out)[i] = o;
}

extern "C" void kernel_launch(void* const* d_in, const int* in_sizes, int n_in,
                              void* d_out, int out_size, void* d_ws, size_t ws_size,
                              hipStream_t stream) {
  const float* x   = (const float*)d_in[0];
  const float* v2  = (const float*)d_in[1];
  const float* Wn1 = (const float*)d_in[2];
  const float* Ws1 = (const float*)d_in[3];
  const float* b1  = (const float*)d_in[4];
  const float* Wn2 = (const float*)d_in[5];
  const float* Ws2 = (const float*)d_in[6];
  const float* b2  = (const float*)d_in[7];
  const float* Wa  = (const float*)d_in[8];
  const float* ba  = (const float*)d_in[9];
  const float* att = (const float*)d_in[10];
  const int*  src  = (const int*)d_in[11];
  const int*  dst  = (const int*)d_in[12];
  const int D = in_sizes[4];        // 128
  const int N = in_sizes[0] / D;    // 50000
  const int E = in_sizes[11];       // 640000
  float* out = (float*)d_out;

  char* ws = (char*)d_ws;
  size_t o = 0;
  auto alloc = [&](size_t bytes) -> void* {
    void* p = ws + o;
    o += (bytes + 255) & ~(size_t)255;
    return p;
  };
  int*  cnt    = (int*)alloc((size_t)N * 4);
  int*  offs   = (int*)alloc((size_t)(N + 1) * 4);
  int*  cursor = (int*)alloc((size_t)N * 4);
  int*  ssrc   = (int*)alloc((size_t)E * 4);
  bf16* xb     = (bf16*)alloc((size_t)N * D * 2);
  bf16* h1b    = (bf16*)alloc((size_t)N * D * 2);
  bf16* wb     = (bf16*)alloc((size_t)5 * D * D * 2);
  float* sc    = (float*)alloc(2 * 4);
  int nb = (N + 255) / 256;
  int*  bsum   = (int*)alloc((size_t)nb * 4);

  int tilesPerView = (N + 15) / 16;          // 3125
  int attnWaves = 2 * tilesPerView;          // 6250
  int nbA = (attnWaves + 3) / 4;             // 1563 blocks
  float* apart = (float*)alloc((size_t)2 * nbA * 4);

  // fused prologue
  int nbZ = (N + 255) / 256;                 // zero cnt
  int nbW = (5 * D * D + 255) / 256;         // weights -> bf16
  int nbX = (N * D / 8 + 255) / 256;         // x -> bf16
  k_prep<<<nbZ + nbW + nbX, 256, 0, stream>>>(cnt, N, Ws1, Wn1, Ws2, Wn2, Wa, wb,
                                              5 * D * D, x, xb, N * D / 8, nbZ, nbW);

  k_hist<<<(E + 255) / 256, 256, 0, stream>>>(dst, cnt, E);
  k_scan1<<<nb, 256, 0, stream>>>(cnt, bsum, N);
  k_scan2<<<1, 256, 0, stream>>>(bsum, nb);
  k_scan3<<<nb, 256, 0, stream>>>(cnt, bsum, offs, cursor, N);
  k_scatter<<<(E + 255) / 256, 256, 0, stream>>>(src, dst, cursor, ssrc, E);

  int tiles = (N + 15) / 16;                 // 3125 row tiles
  int layerBlocks = (tiles + 7) / 8;         // 8 tiles (waves) per block

  // layer 1: h1 (bf16) = x@Ws1^T + mean_nb(x)@Wn1^T + b1
  k_layer<0><<<layerBlocks, 512, 0, stream>>>(xb, offs, ssrc, wb, wb + D * D, b1,
                                              nullptr, h1b, nullptr, N);
  // layer 2: res = x + h1 + 0.5*h2 (f32 in d_out)
  k_layer<1><<<layerBlocks, 512, 0, stream>>>(h1b, offs, ssrc, wb + 2 * D * D,
                                              wb + 3 * D * D, b2, x, nullptr, out, N);
  // fused attention scores over [res, view2]
  k_attn2<<<nbA, 256, 0, stream>>>(out, v2, wb + 4 * D * D, ba, att, apart, nbA, N);
  k_score<<<1, 256, 0, stream>>>(apart, sc, nbA);
  // final blend
  k_fin<<<((N * D / 4) + 255) / 256, 256, 0, stream>>>(out, v2, sc, 1.0f / (float)N, N * D / 4);
}

// Round 10
// 199.394 us; speedup vs baseline: 1.1578x; 1.1578x over previous
//
#include <hip/hip_runtime.h>

#define DD 128

using bf16 = __bf16;
typedef __bf16 bf16x8 __attribute__((ext_vector_type(8)));
typedef float f32x4 __attribute__((ext_vector_type(4)));

__device__ inline bf16x8 cvt8(const float* p) {
  f32x4 v0 = *(const f32x4*)p;
  f32x4 v1 = *(const f32x4*)(p + 4);
  bf16x8 r;
  r[0] = (bf16)v0[0]; r[1] = (bf16)v0[1]; r[2] = (bf16)v0[2]; r[3] = (bf16)v0[3];
  r[4] = (bf16)v1[0]; r[5] = (bf16)v1[1]; r[6] = (bf16)v1[2]; r[7] = (bf16)v1[3];
  return r;
}

// fast tanh: 1 - 2/(e^{2x}+1); v_exp + v_rcp, saturates correctly at +-1
__device__ inline float ftanh(float x) {
  float e2 = __expf(2.0f * x);
  return 1.0f - 2.0f * __builtin_amdgcn_rcpf(e2 + 1.0f);
}

// XOR swizzle for [128 rows][256 B] LDS tiles (G4): spreads 16-row b128
// reads across banks; involution, keeps 16-B alignment.
__device__ inline int swz(int o) { return o ^ (((o >> 8) & 7) << 4); }

// ---- fused prologue: zero cnt | weights->bf16 | x->bf16 ------------------
__global__ void k_prep(int* __restrict__ cnt, int N,
                       const float* __restrict__ w0, const float* __restrict__ w1,
                       const float* __restrict__ w2, const float* __restrict__ w3,
                       const float* __restrict__ w4, bf16* __restrict__ wb, int totalW,
                       const float* __restrict__ x, bf16* __restrict__ xb, int total8,
                       int nbZ, int nbW) {
  int b = blockIdx.x;
  if (b < nbZ) {
    int i = b * 256 + threadIdx.x;
    if (i < N) cnt[i] = 0;
  } else if (b < nbZ + nbW) {
    int i = (b - nbZ) * 256 + threadIdx.x;
    if (i < totalW) {
      int m = i >> 14;           // DD*DD = 16384
      int r = i & 16383;
      const float* s = m == 0 ? w0 : m == 1 ? w1 : m == 2 ? w2 : m == 3 ? w3 : w4;
      wb[i] = (bf16)s[r];
    }
  } else {
    int i = (b - nbZ - nbW) * 256 + threadIdx.x;
    if (i < total8) *(bf16x8*)(xb + (size_t)i * 8) = cvt8(x + (size_t)i * 8);
  }
}

// ---- CSR build ----------------------------------------------------------
__global__ void k_hist(const int* __restrict__ dst, int* __restrict__ cnt, int E) {
  int e = blockIdx.x * 256 + threadIdx.x;
  if (e < E) atomicAdd(&cnt[dst[e]], 1);
}

__global__ __launch_bounds__(256) void k_scan1(const int* __restrict__ cnt,
                                               int* __restrict__ bsum, int N) {
  __shared__ int sm[256];
  int t = threadIdx.x;
  int i = blockIdx.x * 256 + t;
  sm[t] = (i < N) ? cnt[i] : 0;
  __syncthreads();
#pragma unroll
  for (int d = 128; d > 0; d >>= 1) {
    if (t < d) sm[t] += sm[t + d];
    __syncthreads();
  }
  if (t == 0) bsum[blockIdx.x] = sm[0];
}

__global__ __launch_bounds__(256) void k_scan2(int* __restrict__ bsum, int nb) {
  __shared__ int sm[256];
  int t = threadIdx.x;
  int v = (t < nb) ? bsum[t] : 0;
  sm[t] = v;
  __syncthreads();
#pragma unroll
  for (int d = 1; d < 256; d <<= 1) {
    int u = (t >= d) ? sm[t - d] : 0;
    __syncthreads();
    sm[t] += u;
    __syncthreads();
  }
  if (t < nb) bsum[t] = sm[t] - v;   // exclusive prefix
}

__global__ __launch_bounds__(256) void k_scan3(const int* __restrict__ cnt,
                                               const int* __restrict__ bsum,
                                               int* __restrict__ offs,
                                               int* __restrict__ cursor, int N) {
  __shared__ int sm[256];
  int t = threadIdx.x;
  int i = blockIdx.x * 256 + t;
  int v = (i < N) ? cnt[i] : 0;
  sm[t] = v;
  __syncthreads();
#pragma unroll
  for (int d = 1; d < 256; d <<= 1) {
    int u = (t >= d) ? sm[t - d] : 0;
    __syncthreads();
    sm[t] += u;
    __syncthreads();
  }
  int incl = sm[t];
  int base = bsum[blockIdx.x];
  if (i < N) {
    int ex = base + incl - v;
    offs[i] = ex;
    cursor[i] = ex;
    if (i == N - 1) offs[N] = base + incl;
  }
}

__global__ void k_scatter(const int* __restrict__ src, const int* __restrict__ dst,
                          int* __restrict__ cursor, int* __restrict__ ssrc, int E) {
  int e = blockIdx.x * 256 + threadIdx.x;
  if (e < E) {
    int d = dst[e];
    int p = atomicAdd(&cursor[d], 1);
    ssrc[p] = src[e];
  }
}

// ---- fused SAGE layer: aggregate + GEMM ---------------------------------
// Block = 512 threads (8 waves), Ws+Wn staged in 64 KB swizzled LDS.
// Each wave owns 16 nodes. Each 4-lane group (same lane&15) aggregates its
// node's neighbor mean directly into MFMA A-fragment registers, then the
// wave runs the 16x128 GEMM.  (R9's x4 unroll regressed; simple loop.)
// MODE 0: H1out[idx] = (bf16)v
// MODE 1: Out[idx] = Xres[idx] + (f32)Hb[idx] + 0.5*v   (res, f32)
template <int MODE>
__global__ __launch_bounds__(512, 1) void k_layer(const bf16* __restrict__ Hb,
                                                  const int* __restrict__ offs,
                                                  const int* __restrict__ ssrc,
                                                  const bf16* __restrict__ Wsb,
                                                  const bf16* __restrict__ Wnb,
                                                  const float* __restrict__ bias,
                                                  const float* __restrict__ Xres,
                                                  bf16* __restrict__ H1out,
                                                  float* __restrict__ Out, int N) {
  __shared__ char smem[65536];   // [2][128 rows][256 B], swizzled
  int t = threadIdx.x;
#pragma unroll
  for (int m = 0; m < 2; ++m) {
    const bf16* wsrc = m ? Wnb : Wsb;
#pragma unroll
    for (int it = 0; it < 4; ++it) {
      int o = (it * 512 + t) * 16;          // linear byte offset in matrix
      *(bf16x8*)(smem + m * 32768 + swz(o)) = *(const bf16x8*)(wsrc + o / 2);
    }
  }
  __syncthreads();

  int wv = t >> 6;
  int lane = t & 63;
  int tile = blockIdx.x * 8 + wv;
  int n0 = tile << 4;
  if (n0 >= N) return;
  int lr = lane & 15;
  int g = lane >> 4;
  int lk = g << 3;                          // k offset in elems (8-elem chunk)

  // A1 (self) fragments
  const bf16* a1p = Hb + (size_t)(n0 + lr) * DD + lk;
  bf16x8 a1[4];
#pragma unroll
  for (int kk = 0; kk < 4; ++kk) a1[kk] = *(const bf16x8*)(a1p + kk * 32);

  // aggregate neighbor mean for node n0+lr into A2 fragments (f32 acc)
  int node = n0 + lr;
  int beg = offs[node], end = offs[node + 1];
  float acc[4][8];
#pragma unroll
  for (int kk = 0; kk < 4; ++kk)
#pragma unroll
    for (int j = 0; j < 8; ++j) acc[kk][j] = 0.f;
  for (int i = beg; i < end; ++i) {
    int s = ssrc[i];
    const bf16* hp = Hb + (size_t)s * DD + lk;
#pragma unroll
    for (int kk = 0; kk < 4; ++kk) {
      bf16x8 v = *(const bf16x8*)(hp + kk * 32);
#pragma unroll
      for (int j = 0; j < 8; ++j) acc[kk][j] += (float)v[j];
    }
  }
  float inv = (end > beg) ? 1.0f / (float)(end - beg) : 0.f;
  bf16x8 a2[4];
#pragma unroll
  for (int kk = 0; kk < 4; ++kk)
#pragma unroll
    for (int j = 0; j < 8; ++j) a2[kk][j] = (bf16)(acc[kk][j] * inv);

  int rb = n0 + (g << 2);
#pragma unroll
  for (int j = 0; j < 8; ++j) {
    int row = j * 16 + lr;
    int rbase = row * 256 + lk * 2;         // byte offset of this lane's chunk
    f32x4 cs = {0.f, 0.f, 0.f, 0.f};
    f32x4 cn = {0.f, 0.f, 0.f, 0.f};
#pragma unroll
    for (int kk = 0; kk < 4; ++kk) {
      int ro = swz(rbase + kk * 64);
      bf16x8 bs = *(const bf16x8*)(smem + ro);
      bf16x8 bn = *(const bf16x8*)(smem + 32768 + ro);
      cs = __builtin_amdgcn_mfma_f32_16x16x32_bf16(a1[kk], bs, cs, 0, 0, 0);
      cn = __builtin_amdgcn_mfma_f32_16x16x32_bf16(a2[kk], bn, cn, 0, 0, 0);
    }
    int col = j * 16 + lr;
    float bb = bias[col];
#pragma unroll
    for (int r = 0; r < 4; ++r) {
      size_t idx = (size_t)(rb + r) * DD + col;
      float v = cs[r] + cn[r] + bb;
      if (MODE == 0) H1out[idx] = (bf16)v;
      else           Out[idx] = Xres[idx] + (float)Hb[idx] + 0.5f * v;
    }
  }
}

// ---- fused attention scores, LDS-staged W_attn --------------------------
// Block = 512 threads (8 waves); Wa staged in 32 KB swizzled LDS.
// Wave wv handles (tile, view) with gwid = blockIdx*8+wv; view = gwid&1.
__global__ __launch_bounds__(512, 4) void k_attn2(const float* __restrict__ res,
                                                  const float* __restrict__ v2f,
                                                  const bf16* __restrict__ Wab,
                                                  const float* __restrict__ bias,
                                                  const float* __restrict__ att,
                                                  float* __restrict__ partial,
                                                  int nbA, int N) {
  __shared__ char smem[32768];   // [128 rows][256 B], swizzled
  __shared__ float smr[8];
  int t = threadIdx.x;
#pragma unroll
  for (int it = 0; it < 4; ++it) {
    int o = (it * 512 + t) * 16;            // linear byte offset in matrix
    *(bf16x8*)(smem + swz(o)) = *(const bf16x8*)(Wab + o / 2);
  }
  __syncthreads();

  int wv = t >> 6;
  int lane = t & 63;
  int gwid = blockIdx.x * 8 + wv;
  int view = gwid & 1;
  int tile = gwid >> 1;
  int n0 = tile << 4;
  float part = 0.f;
  if (n0 < N) {
    const float* Ef = view ? v2f : res;
    int lr = lane & 15;
    int lk = (lane >> 4) << 3;
    const float* ap = Ef + (size_t)(n0 + lr) * DD + lk;
    bf16x8 a[4];
#pragma unroll
    for (int kk = 0; kk < 4; ++kk) a[kk] = cvt8(ap + kk * 32);
#pragma unroll
    for (int j = 0; j < 8; ++j) {
      int row = j * 16 + lr;
      int rbase = row * 256 + lk * 2;
      f32x4 c = {0.f, 0.f, 0.f, 0.f};
#pragma unroll
      for (int kk = 0; kk < 4; ++kk) {
        bf16x8 bw = *(const bf16x8*)(smem + swz(rbase + kk * 64));
        c = __builtin_amdgcn_mfma_f32_16x16x32_bf16(a[kk], bw, c, 0, 0, 0);
      }
      int col = j * 16 + lr;
      float aw = att[col], bb = bias[col];
#pragma unroll
      for (int r = 0; r < 4; ++r) part += aw * ftanh(c[r] + bb);
    }
  }
#pragma unroll
  for (int d = 1; d < 64; d <<= 1) part += __shfl_xor(part, d);
  if (lane == 0) smr[wv] = part;
  __syncthreads();
  if (t == 0) {
    partial[blockIdx.x]       = smr[0] + smr[2] + smr[4] + smr[6];  // view 0
    partial[nbA + blockIdx.x] = smr[1] + smr[3] + smr[5] + smr[7];  // view 1
  }
}

// ---- reduce partials -> scores[2] ---------------------------------------
__global__ __launch_bounds__(256) void k_score(const float* __restrict__ partial,
                                               float* __restrict__ scores, int nbA) {
  __shared__ float sm[256];
  int t = threadIdx.x;
#pragma unroll
  for (int v = 0; v < 2; ++v) {
    float s = 0.f;
    for (int i = t; i < nbA; i += 256) s += partial[v * nbA + i];
    sm[t] = s;
    __syncthreads();
#pragma unroll
    for (int d = 128; d > 0; d >>= 1) {
      if (t < d) sm[t] += sm[t + d];
      __syncthreads();
    }
    if (t == 0) scores[v] = sm[0];
    __syncthreads();
  }
}

// ---- final blend: out = b0*res + b1*view2 (in place on d_out) -----------
__global__ void k_fin(float* out, const float* __restrict__ v2,
                      const float* __restrict__ scores, float invN, int total4) {
  int i = blockIdx.x * 256 + threadIdx.x;
  if (i >= total4) return;
  float s0 = scores[0] * invN, s1 = scores[1] * invN;
  float m = fmaxf(s0, s1);
  float e0 = expf(s0 - m), e1 = expf(s1 - m);
  float inv = 1.0f / (e0 + e1);
  float b0 = e0 * inv, b1 = e1 * inv;
  f32x4 r = ((const f32x4*)out)[i];
  f32x4 w = ((const f32x4*)v2)[i];
  f32x4 o;
  o[0] = b0 * r[0] + b1 * w[0];
  o[1] = b0 * r[1] + b1 * w[1];
  o[2] = b0 * r[2] + b1 * w[2];
  o[3] = b0 * r[3] + b1 * w[3];
  ((f32x4*)out)[i] = o;
}

extern "C" void kernel_launch(void* const* d_in, const int* in_sizes, int n_in,
                              void* d_out, int out_size, void* d_ws, size_t ws_size,
                              hipStream_t stream) {
  const float* x   = (const float*)d_in[0];
  const float* v2  = (const float*)d_in[1];
  const float* Wn1 = (const float*)d_in[2];
  const float* Ws1 = (const float*)d_in[3];
  const float* b1  = (const float*)d_in[4];
  const float* Wn2 = (const float*)d_in[5];
  const float* Ws2 = (const float*)d_in[6];
  const float* b2  = (const float*)d_in[7];
  const float* Wa  = (const float*)d_in[8];
  const float* ba  = (const float*)d_in[9];
  const float* att = (const float*)d_in[10];
  const int*  src  = (const int*)d_in[11];
  const int*  dst  = (const int*)d_in[12];
  const int D = in_sizes[4];        // 128
  const int N = in_sizes[0] / D;    // 50000
  const int E = in_sizes[11];       // 640000
  float* out = (float*)d_out;

  char* ws = (char*)d_ws;
  size_t o = 0;
  auto alloc = [&](size_t bytes) -> void* {
    void* p = ws + o;
    o += (bytes + 255) & ~(size_t)255;
    return p;
  };
  int*  cnt    = (int*)alloc((size_t)N * 4);
  int*  offs   = (int*)alloc((size_t)(N + 1) * 4);
  int*  cursor = (int*)alloc((size_t)N * 4);
  int*  ssrc   = (int*)alloc((size_t)E * 4);
  bf16* xb     = (bf16*)alloc((size_t)N * D * 2);
  bf16* h1b    = (bf16*)alloc((size_t)N * D * 2);
  bf16* wb     = (bf16*)alloc((size_t)5 * D * D * 2);
  float* sc    = (float*)alloc(2 * 4);
  int nb = (N + 255) / 256;
  int*  bsum   = (int*)alloc((size_t)nb * 4);

  int tilesPerView = (N + 15) / 16;          // 3125
  int attnWaves = 2 * tilesPerView;          // 6250
  int nbA = (attnWaves + 7) / 8;             // 782 blocks (8 waves each)
  float* apart = (float*)alloc((size_t)2 * nbA * 4);

  // fused prologue
  int nbZ = (N + 255) / 256;                 // zero cnt
  int nbW = (5 * D * D + 255) / 256;         // weights -> bf16
  int nbX = (N * D / 8 + 255) / 256;         // x -> bf16
  k_prep<<<nbZ + nbW + nbX, 256, 0, stream>>>(cnt, N, Ws1, Wn1, Ws2, Wn2, Wa, wb,
                                              5 * D * D, x, xb, N * D / 8, nbZ, nbW);

  k_hist<<<(E + 255) / 256, 256, 0, stream>>>(dst, cnt, E);
  k_scan1<<<nb, 256, 0, stream>>>(cnt, bsum, N);
  k_scan2<<<1, 256, 0, stream>>>(bsum, nb);
  k_scan3<<<nb, 256, 0, stream>>>(cnt, bsum, offs, cursor, N);
  k_scatter<<<(E + 255) / 256, 256, 0, stream>>>(src, dst, cursor, ssrc, E);

  int tiles = (N + 15) / 16;                 // 3125 row tiles
  int layerBlocks = (tiles + 7) / 8;         // 8 tiles (waves) per block

  // layer 1: h1 (bf16) = x@Ws1^T + mean_nb(x)@Wn1^T + b1
  k_layer<0><<<layerBlocks, 512, 0, stream>>>(xb, offs, ssrc, wb, wb + D * D, b1,
                                              nullptr, h1b, nullptr, N);
  // layer 2: res = x + h1 + 0.5*h2 (f32 in d_out)
  k_layer<1><<<layerBlocks, 512, 0, stream>>>(h1b, offs, ssrc, wb + 2 * D * D,
                                              wb + 3 * D * D, b2, x, nullptr, out, N);
  // fused attention scores over [res, view2], W_attn LDS-staged
  k_attn2<<<nbA, 512, 0, stream>>>(out, v2, wb + 4 * D * D, ba, att, apart, nbA, N);
  k_score<<<1, 256, 0, stream>>>(apart, sc, nbA);
  // final blend
  k_fin<<<((N * D / 4) + 255) / 256, 256, 0, stream>>>(out, v2, sc, 1.0f / (float)N, N * D / 4);
}

// Round 11
// 195.528 us; speedup vs baseline: 1.1807x; 1.0198x over previous
//
#include <hip/hip_runtime.h>

#define DD 128

using bf16 = __bf16;
typedef __bf16 bf16x8 __attribute__((ext_vector_type(8)));
typedef float f32x4 __attribute__((ext_vector_type(4)));

__device__ inline bf16x8 cvt8(const float* p) {
  f32x4 v0 = *(const f32x4*)p;
  f32x4 v1 = *(const f32x4*)(p + 4);
  bf16x8 r;
  r[0] = (bf16)v0[0]; r[1] = (bf16)v0[1]; r[2] = (bf16)v0[2]; r[3] = (bf16)v0[3];
  r[4] = (bf16)v1[0]; r[5] = (bf16)v1[1]; r[6] = (bf16)v1[2]; r[7] = (bf16)v1[3];
  return r;
}

// fast tanh: 1 - 2/(e^{2x}+1); v_exp + v_rcp, saturates correctly at +-1
__device__ inline float ftanh(float x) {
  float e2 = __expf(2.0f * x);
  return 1.0f - 2.0f * __builtin_amdgcn_rcpf(e2 + 1.0f);
}

// XOR swizzle for [128 rows][256 B] LDS tiles (G4): spreads 16-row b128
// reads across banks; involution, keeps 16-B alignment.
__device__ inline int swz(int o) { return o ^ (((o >> 8) & 7) << 4); }

// ---- fused prologue: zero cnt | weights->bf16 | x->bf16 ------------------
__global__ void k_prep(int* __restrict__ cnt, int N,
                       const float* __restrict__ w0, const float* __restrict__ w1,
                       const float* __restrict__ w2, const float* __restrict__ w3,
                       const float* __restrict__ w4, bf16* __restrict__ wb, int totalW,
                       const float* __restrict__ x, bf16* __restrict__ xb, int total8,
                       int nbZ, int nbW) {
  int b = blockIdx.x;
  if (b < nbZ) {
    int i = b * 256 + threadIdx.x;
    if (i < N) cnt[i] = 0;
  } else if (b < nbZ + nbW) {
    int i = (b - nbZ) * 256 + threadIdx.x;
    if (i < totalW) {
      int m = i >> 14;           // DD*DD = 16384
      int r = i & 16383;
      const float* s = m == 0 ? w0 : m == 1 ? w1 : m == 2 ? w2 : m == 3 ? w3 : w4;
      wb[i] = (bf16)s[r];
    }
  } else {
    int i = (b - nbZ - nbW) * 256 + threadIdx.x;
    if (i < total8) *(bf16x8*)(xb + (size_t)i * 8) = cvt8(x + (size_t)i * 8);
  }
}

// ---- CSR build ----------------------------------------------------------
__global__ void k_hist(const int* __restrict__ dst, int* __restrict__ cnt, int E) {
  int e = blockIdx.x * 256 + threadIdx.x;
  if (e < E) atomicAdd(&cnt[dst[e]], 1);
}

__global__ __launch_bounds__(256) void k_scan1(const int* __restrict__ cnt,
                                               int* __restrict__ bsum, int N) {
  __shared__ int sm[256];
  int t = threadIdx.x;
  int i = blockIdx.x * 256 + t;
  sm[t] = (i < N) ? cnt[i] : 0;
  __syncthreads();
#pragma unroll
  for (int d = 128; d > 0; d >>= 1) {
    if (t < d) sm[t] += sm[t + d];
    __syncthreads();
  }
  if (t == 0) bsum[blockIdx.x] = sm[0];
}

__global__ __launch_bounds__(256) void k_scan2(int* __restrict__ bsum, int nb) {
  __shared__ int sm[256];
  int t = threadIdx.x;
  int v = (t < nb) ? bsum[t] : 0;
  sm[t] = v;
  __syncthreads();
#pragma unroll
  for (int d = 1; d < 256; d <<= 1) {
    int u = (t >= d) ? sm[t - d] : 0;
    __syncthreads();
    sm[t] += u;
    __syncthreads();
  }
  if (t < nb) bsum[t] = sm[t] - v;   // exclusive prefix
}

__global__ __launch_bounds__(256) void k_scan3(const int* __restrict__ cnt,
                                               const int* __restrict__ bsum,
                                               int* __restrict__ offs,
                                               int* __restrict__ cursor, int N) {
  __shared__ int sm[256];
  int t = threadIdx.x;
  int i = blockIdx.x * 256 + t;
  int v = (i < N) ? cnt[i] : 0;
  sm[t] = v;
  __syncthreads();
#pragma unroll
  for (int d = 1; d < 256; d <<= 1) {
    int u = (t >= d) ? sm[t - d] : 0;
    __syncthreads();
    sm[t] += u;
    __syncthreads();
  }
  int incl = sm[t];
  int base = bsum[blockIdx.x];
  if (i < N) {
    int ex = base + incl - v;
    offs[i] = ex;
    cursor[i] = ex;
    if (i == N - 1) offs[N] = base + incl;
  }
}

__global__ void k_scatter(const int* __restrict__ src, const int* __restrict__ dst,
                          int* __restrict__ cursor, int* __restrict__ ssrc, int E) {
  int e = blockIdx.x * 256 + threadIdx.x;
  if (e < E) {
    int d = dst[e];
    int p = atomicAdd(&cursor[d], 1);
    ssrc[p] = src[e];
  }
}

// ---- fused SAGE layer: aggregate + GEMM ---------------------------------
// Block = 1024 threads (16 waves), Ws+Wn staged in 64 KB swizzled LDS.
// 16 waves/CU (grid ~= 1 block/CU) to hide gather latency.
// Each wave owns 16 nodes; 4-lane groups aggregate the neighbor mean
// directly into MFMA A-fragment registers, then run the 16x128 GEMM.
// MODE 0: H1out[idx] = (bf16)v
// MODE 1: Out[idx] = Xres[idx] + (f32)Hb[idx] + 0.5*v   (res, f32)
template <int MODE>
__global__ __launch_bounds__(1024, 1) void k_layer(const bf16* __restrict__ Hb,
                                                   const int* __restrict__ offs,
                                                   const int* __restrict__ ssrc,
                                                   const bf16* __restrict__ Wsb,
                                                   const bf16* __restrict__ Wnb,
                                                   const float* __restrict__ bias,
                                                   const float* __restrict__ Xres,
                                                   bf16* __restrict__ H1out,
                                                   float* __restrict__ Out, int N) {
  __shared__ char smem[65536];   // [2][128 rows][256 B], swizzled
  int t = threadIdx.x;
#pragma unroll
  for (int m = 0; m < 2; ++m) {
    const bf16* wsrc = m ? Wnb : Wsb;
#pragma unroll
    for (int it = 0; it < 2; ++it) {
      int o = (it * 1024 + t) * 16;         // linear byte offset in matrix
      *(bf16x8*)(smem + m * 32768 + swz(o)) = *(const bf16x8*)(wsrc + o / 2);
    }
  }
  __syncthreads();

  int wv = t >> 6;
  int lane = t & 63;
  int tile = blockIdx.x * 16 + wv;
  int n0 = tile << 4;
  if (n0 >= N) return;
  int lr = lane & 15;
  int g = lane >> 4;
  int lk = g << 3;                          // k offset in elems (8-elem chunk)

  // A1 (self) fragments
  const bf16* a1p = Hb + (size_t)(n0 + lr) * DD + lk;
  bf16x8 a1[4];
#pragma unroll
  for (int kk = 0; kk < 4; ++kk) a1[kk] = *(const bf16x8*)(a1p + kk * 32);

  // aggregate neighbor mean for node n0+lr into A2 fragments (f32 acc)
  int node = n0 + lr;
  int beg = offs[node], end = offs[node + 1];
  float acc[4][8];
#pragma unroll
  for (int kk = 0; kk < 4; ++kk)
#pragma unroll
    for (int j = 0; j < 8; ++j) acc[kk][j] = 0.f;
  for (int i = beg; i < end; ++i) {
    int s = ssrc[i];
    const bf16* hp = Hb + (size_t)s * DD + lk;
#pragma unroll
    for (int kk = 0; kk < 4; ++kk) {
      bf16x8 v = *(const bf16x8*)(hp + kk * 32);
#pragma unroll
      for (int j = 0; j < 8; ++j) acc[kk][j] += (float)v[j];
    }
  }
  float inv = (end > beg) ? 1.0f / (float)(end - beg) : 0.f;
  bf16x8 a2[4];
#pragma unroll
  for (int kk = 0; kk < 4; ++kk)
#pragma unroll
    for (int j = 0; j < 8; ++j) a2[kk][j] = (bf16)(acc[kk][j] * inv);

  int rb = n0 + (g << 2);
#pragma unroll
  for (int j = 0; j < 8; ++j) {
    int row = j * 16 + lr;
    int rbase = row * 256 + lk * 2;         // byte offset of this lane's chunk
    f32x4 cs = {0.f, 0.f, 0.f, 0.f};
    f32x4 cn = {0.f, 0.f, 0.f, 0.f};
#pragma unroll
    for (int kk = 0; kk < 4; ++kk) {
      int ro = swz(rbase + kk * 64);
      bf16x8 bs = *(const bf16x8*)(smem + ro);
      bf16x8 bn = *(const bf16x8*)(smem + 32768 + ro);
      cs = __builtin_amdgcn_mfma_f32_16x16x32_bf16(a1[kk], bs, cs, 0, 0, 0);
      cn = __builtin_amdgcn_mfma_f32_16x16x32_bf16(a2[kk], bn, cn, 0, 0, 0);
    }
    int col = j * 16 + lr;
    float bb = bias[col];
#pragma unroll
    for (int r = 0; r < 4; ++r) {
      size_t idx = (size_t)(rb + r) * DD + col;
      float v = cs[r] + cn[r] + bb;
      if (MODE == 0) H1out[idx] = (bf16)v;
      else           Out[idx] = Xres[idx] + (float)Hb[idx] + 0.5f * v;
    }
  }
}

// ---- fused attention scores, LDS-staged W_attn --------------------------
// Block = 512 threads (8 waves); Wa staged in 32 KB swizzled LDS.
// Wave wv handles (tile, view) with gwid = blockIdx*8+wv; view = gwid&1.
__global__ __launch_bounds__(512, 4) void k_attn2(const float* __restrict__ res,
                                                  const float* __restrict__ v2f,
                                                  const bf16* __restrict__ Wab,
                                                  const float* __restrict__ bias,
                                                  const float* __restrict__ att,
                                                  float* __restrict__ partial,
                                                  int nbA, int N) {
  __shared__ char smem[32768];   // [128 rows][256 B], swizzled
  __shared__ float smr[8];
  int t = threadIdx.x;
#pragma unroll
  for (int it = 0; it < 4; ++it) {
    int o = (it * 512 + t) * 16;            // linear byte offset in matrix
    *(bf16x8*)(smem + swz(o)) = *(const bf16x8*)(Wab + o / 2);
  }
  __syncthreads();

  int wv = t >> 6;
  int lane = t & 63;
  int gwid = blockIdx.x * 8 + wv;
  int view = gwid & 1;
  int tile = gwid >> 1;
  int n0 = tile << 4;
  float part = 0.f;
  if (n0 < N) {
    const float* Ef = view ? v2f : res;
    int lr = lane & 15;
    int lk = (lane >> 4) << 3;
    const float* ap = Ef + (size_t)(n0 + lr) * DD + lk;
    bf16x8 a[4];
#pragma unroll
    for (int kk = 0; kk < 4; ++kk) a[kk] = cvt8(ap + kk * 32);
#pragma unroll
    for (int j = 0; j < 8; ++j) {
      int row = j * 16 + lr;
      int rbase = row * 256 + lk * 2;
      f32x4 c = {0.f, 0.f, 0.f, 0.f};
#pragma unroll
      for (int kk = 0; kk < 4; ++kk) {
        bf16x8 bw = *(const bf16x8*)(smem + swz(rbase + kk * 64));
        c = __builtin_amdgcn_mfma_f32_16x16x32_bf16(a[kk], bw, c, 0, 0, 0);
      }
      int col = j * 16 + lr;
      float aw = att[col], bb = bias[col];
#pragma unroll
      for (int r = 0; r < 4; ++r) part += aw * ftanh(c[r] + bb);
    }
  }
#pragma unroll
  for (int d = 1; d < 64; d <<= 1) part += __shfl_xor(part, d);
  if (lane == 0) smr[wv] = part;
  __syncthreads();
  if (t == 0) {
    partial[blockIdx.x]       = smr[0] + smr[2] + smr[4] + smr[6];  // view 0
    partial[nbA + blockIdx.x] = smr[1] + smr[3] + smr[5] + smr[7];  // view 1
  }
}

// ---- reduce partials -> scores[2] ---------------------------------------
__global__ __launch_bounds__(256) void k_score(const float* __restrict__ partial,
                                               float* __restrict__ scores, int nbA) {
  __shared__ float sm[256];
  int t = threadIdx.x;
#pragma unroll
  for (int v = 0; v < 2; ++v) {
    float s = 0.f;
    for (int i = t; i < nbA; i += 256) s += partial[v * nbA + i];
    sm[t] = s;
    __syncthreads();
#pragma unroll
    for (int d = 128; d > 0; d >>= 1) {
      if (t < d) sm[t] += sm[t + d];
      __syncthreads();
    }
    if (t == 0) scores[v] = sm[0];
    __syncthreads();
  }
}

// ---- final blend: out = b0*res + b1*view2 (in place on d_out) -----------
__global__ void k_fin(float* out, const float* __restrict__ v2,
                      const float* __restrict__ scores, float invN, int total4) {
  int i = blockIdx.x * 256 + threadIdx.x;
  if (i >= total4) return;
  float s0 = scores[0] * invN, s1 = scores[1] * invN;
  float m = fmaxf(s0, s1);
  float e0 = expf(s0 - m), e1 = expf(s1 - m);
  float inv = 1.0f / (e0 + e1);
  float b0 = e0 * inv, b1 = e1 * inv;
  f32x4 r = ((const f32x4*)out)[i];
  f32x4 w = ((const f32x4*)v2)[i];
  f32x4 o;
  o[0] = b0 * r[0] + b1 * w[0];
  o[1] = b0 * r[1] + b1 * w[1];
  o[2] = b0 * r[2] + b1 * w[2];
  o[3] = b0 * r[3] + b1 * w[3];
  ((f32x4*)out)[i] = o;
}

extern "C" void kernel_launch(void* const* d_in, const int* in_sizes, int n_in,
                              void* d_out, int out_size, void* d_ws, size_t ws_size,
                              hipStream_t stream) {
  const float* x   = (const float*)d_in[0];
  const float* v2  = (const float*)d_in[1];
  const float* Wn1 = (const float*)d_in[2];
  const float* Ws1 = (const float*)d_in[3];
  const float* b1  = (const float*)d_in[4];
  const float* Wn2 = (const float*)d_in[5];
  const float* Ws2 = (const float*)d_in[6];
  const float* b2  = (const float*)d_in[7];
  const float* Wa  = (const float*)d_in[8];
  const float* ba  = (const float*)d_in[9];
  const float* att = (const float*)d_in[10];
  const int*  src  = (const int*)d_in[11];
  const int*  dst  = (const int*)d_in[12];
  const int D = in_sizes[4];        // 128
  const int N = in_sizes[0] / D;    // 50000
  const int E = in_sizes[11];       // 640000
  float* out = (float*)d_out;

  char* ws = (char*)d_ws;
  size_t o = 0;
  auto alloc = [&](size_t bytes) -> void* {
    void* p = ws + o;
    o += (bytes + 255) & ~(size_t)255;
    return p;
  };
  int*  cnt    = (int*)alloc((size_t)N * 4);
  int*  offs   = (int*)alloc((size_t)(N + 1) * 4);
  int*  cursor = (int*)alloc((size_t)N * 4);
  int*  ssrc   = (int*)alloc((size_t)E * 4);
  bf16* xb     = (bf16*)alloc((size_t)N * D * 2);
  bf16* h1b    = (bf16*)alloc((size_t)N * D * 2);
  bf16* wb     = (bf16*)alloc((size_t)5 * D * D * 2);
  float* sc    = (float*)alloc(2 * 4);
  int nb = (N + 255) / 256;
  int*  bsum   = (int*)alloc((size_t)nb * 4);

  int tilesPerView = (N + 15) / 16;          // 3125
  int attnWaves = 2 * tilesPerView;          // 6250
  int nbA = (attnWaves + 7) / 8;             // 782 blocks (8 waves each)
  float* apart = (float*)alloc((size_t)2 * nbA * 4);

  // fused prologue
  int nbZ = (N + 255) / 256;                 // zero cnt
  int nbW = (5 * D * D + 255) / 256;         // weights -> bf16
  int nbX = (N * D / 8 + 255) / 256;         // x -> bf16
  k_prep<<<nbZ + nbW + nbX, 256, 0, stream>>>(cnt, N, Ws1, Wn1, Ws2, Wn2, Wa, wb,
                                              5 * D * D, x, xb, N * D / 8, nbZ, nbW);

  k_hist<<<(E + 255) / 256, 256, 0, stream>>>(dst, cnt, E);
  k_scan1<<<nb, 256, 0, stream>>>(cnt, bsum, N);
  k_scan2<<<1, 256, 0, stream>>>(bsum, nb);
  k_scan3<<<nb, 256, 0, stream>>>(cnt, bsum, offs, cursor, N);
  k_scatter<<<(E + 255) / 256, 256, 0, stream>>>(src, dst, cursor, ssrc, E);

  int tiles = (N + 15) / 16;                 // 3125 row tiles
  int layerBlocks = (tiles + 15) / 16;       // 16 tiles (waves) per block

  // layer 1: h1 (bf16) = x@Ws1^T + mean_nb(x)@Wn1^T + b1
  k_layer<0><<<layerBlocks, 1024, 0, stream>>>(xb, offs, ssrc, wb, wb + D * D, b1,
                                               nullptr, h1b, nullptr, N);
  // layer 2: res = x + h1 + 0.5*h2 (f32 in d_out)
  k_layer<1><<<layerBlocks, 1024, 0, stream>>>(h1b, offs, ssrc, wb + 2 * D * D,
                                               wb + 3 * D * D, b2, x, nullptr, out, N);
  // fused attention scores over [res, view2], W_attn LDS-staged
  k_attn2<<<nbA, 512, 0, stream>>>(out, v2, wb + 4 * D * D, ba, att, apart, nbA, N);
  k_score<<<1, 256, 0, stream>>>(apart, sc, nbA);
  // final blend
  k_fin<<<((N * D / 4) + 255) / 256, 256, 0, stream>>>(out, v2, sc, 1.0f / (float)N, N * D / 4);
}